// Round 8
// baseline (844.378 us; speedup 1.0000x reference)
//
#include <hip/hip_runtime.h>
#include <hip/hip_bf16.h>

#define N 4096
#define C 512

typedef __attribute__((ext_vector_type(8))) short bf16x8;
typedef __attribute__((ext_vector_type(8))) short s16x8;
typedef __attribute__((ext_vector_type(4))) float f32x4;

__device__ inline float bf2f(__hip_bfloat16 h) { return __bfloat162float(h); }

__device__ inline void gload16(const void* g, void* l) {
    __builtin_amdgcn_global_load_lds(
        (__attribute__((address_space(1))) void*)(g),
        (__attribute__((address_space(3))) void*)(l),
        16, 0, 0);
}

// ================= kernel 1: single-pass paired prep ==========================
// 512 blocks x 256 threads. pair = b>>8 (0: v&pt -> dv, 1: t&pv -> dt),
// chunk = b&255 (16 rows). Wave w owns rows chunk*16 + w*4 .. +3.
__global__ __launch_bounds__(256) void k_prep(
    const float* __restrict__ s0, const float* __restrict__ s1f,
    const float* __restrict__ s2f, const float* __restrict__ s3,
    __hip_bfloat16* __restrict__ ws_hi0, long mat_stride,
    float* __restrict__ dv, float* __restrict__ dt,
    float* __restrict__ colsum, float* __restrict__ colsq)
{
    __shared__ float sa[4][512];
    __shared__ float sq[4][512];

    const int b = blockIdx.x;
    const int tid = threadIdx.x;
    const int lane = tid & 63;
    const int w = tid >> 6;

    const int pair = b >> 8;
    const int chunk = b & 255;
    const float* X = pair ? s1f : s0;        // t : v
    const float* B = pair ? s2f : s3;        // pv : pt
    const int mX = pair ? 1 : 0;
    const int mB = pair ? 2 : 3;
    __hip_bfloat16* hiX = ws_hi0 + (long)mX * mat_stride;
    __hip_bfloat16* loX = hiX + (long)N * C;
    __hip_bfloat16* hiB = ws_hi0 + (long)mB * mat_stride;
    __hip_bfloat16* loB = hiB + (long)N * C;
    float* dout = pair ? dt : dv;

    float aX[8], qX[8], aB[8], qB[8];
    for (int e = 0; e < 8; e++) { aX[e] = 0.f; qX[e] = 0.f; aB[e] = 0.f; qB[e] = 0.f; }

    const int row0 = chunk * 16 + w * 4;
    for (int i = 0; i < 4; i++) {
        const int row = row0 + i;
        const float4* x4 = (const float4*)(X + (size_t)row * C);
        const float4* b4 = (const float4*)(B + (size_t)row * C);
        float4 x0 = x4[lane * 2], x1 = x4[lane * 2 + 1];
        float4 b0 = b4[lane * 2], b1 = b4[lane * 2 + 1];

        float ss  = x0.x*x0.x + x0.y*x0.y + x0.z*x0.z + x0.w*x0.w
                  + x1.x*x1.x + x1.y*x1.y + x1.z*x1.z + x1.w*x1.w;
        float ssb = b0.x*b0.x + b0.y*b0.y + b0.z*b0.z + b0.w*b0.w
                  + b1.x*b1.x + b1.y*b1.y + b1.z*b1.z + b1.w*b1.w;
        float dot = x0.x*b0.x + x0.y*b0.y + x0.z*b0.z + x0.w*b0.w
                  + x1.x*b1.x + x1.y*b1.y + x1.z*b1.z + x1.w*b1.w;
        for (int o = 1; o < 64; o <<= 1) {       // 3 independent chains, interleaved
            ss  += __shfl_xor(ss, o);
            ssb += __shfl_xor(ssb, o);
            dot += __shfl_xor(dot, o);
        }
        float scX = 1.0f / fmaxf(sqrtf(ss), 1e-12f);
        float scB = 1.0f / fmaxf(sqrtf(ssb), 1e-12f);
        if (lane == 0) dout[row] = dot * scX * scB;

        float yx[8] = { x0.x*scX, x0.y*scX, x0.z*scX, x0.w*scX,
                        x1.x*scX, x1.y*scX, x1.z*scX, x1.w*scX };
        float yb[8] = { b0.x*scB, b0.y*scB, b0.z*scB, b0.w*scB,
                        b1.x*scB, b1.y*scB, b1.z*scB, b1.w*scB };
        __hip_bfloat16 hvx[8], lvx[8], hvb[8], lvb[8];
        for (int e = 0; e < 8; e++) {
            hvx[e] = __float2bfloat16(yx[e]);
            lvx[e] = __float2bfloat16(yx[e] - bf2f(hvx[e]));
            aX[e] += yx[e]; qX[e] += yx[e] * yx[e];
            hvb[e] = __float2bfloat16(yb[e]);
            lvb[e] = __float2bfloat16(yb[e] - bf2f(hvb[e]));
            aB[e] += yb[e]; qB[e] += yb[e] * yb[e];
        }
        size_t base = (size_t)row * C + lane * 8;
        *(s16x8*)(hiX + base) = *(s16x8*)hvx;
        *(s16x8*)(loX + base) = *(s16x8*)lvx;
        *(s16x8*)(hiB + base) = *(s16x8*)hvb;
        *(s16x8*)(loB + base) = *(s16x8*)lvb;
    }

    for (int e = 0; e < 8; e++) { sa[w][lane*8+e] = aX[e]; sq[w][lane*8+e] = qX[e]; }
    __syncthreads();
    for (int c = tid; c < 512; c += 256) {
        atomicAdd(&colsum[mX * 512 + c], sa[0][c] + sa[1][c] + sa[2][c] + sa[3][c]);
        atomicAdd(&colsq [mX * 512 + c], sq[0][c] + sq[1][c] + sq[2][c] + sq[3][c]);
    }
    __syncthreads();
    for (int e = 0; e < 8; e++) { sa[w][lane*8+e] = aB[e]; sq[w][lane*8+e] = qB[e]; }
    __syncthreads();
    for (int c = tid; c < 512; c += 256) {
        atomicAdd(&colsum[mB * 512 + c], sa[0][c] + sa[1][c] + sa[2][c] + sa[3][c]);
        atomicAdd(&colsq [mB * 512 + c], sq[0][c] + sq[1][c] + sq[2][c] + sq[3][c]);
    }
}

// ================= kernel 2: fused split-GEMM + epilogue + last-block fin =====
// C-tile 128x128, BK=32, 4 waves (2x2), 3 MFMA per frag pair.
// XOR k-block swizzle (verified: SQ_LDS_BANK_CONFLICT == 0).
// LDS exactly 32 KB (sA+sB); sdiag/sred/fin-reductions OVERLAY sA post-K-loop
// -> 5 blocks/CU (was 4 at 35328 B). __launch_bounds__(256,5) caps VGPR at 102.
// Last block (device atomic counter == 2047) computes the 13 outputs.
__global__ __launch_bounds__(256, 5) void k_gemm(
    const __hip_bfloat16* __restrict__ h0, const __hip_bfloat16* __restrict__ l0,
    const __hip_bfloat16* __restrict__ h1, const __hip_bfloat16* __restrict__ l1,
    const __hip_bfloat16* __restrict__ h2, const __hip_bfloat16* __restrict__ l2,
    const __hip_bfloat16* __restrict__ h3, const __hip_bfloat16* __restrict__ l3,
    const float* __restrict__ dv, const float* __restrict__ dt,
    float* __restrict__ row_ev, float* __restrict__ row_et,
    float* __restrict__ row_cv, float* __restrict__ row_ct,
    const float* __restrict__ colsum, const float* __restrict__ colsq,
    unsigned int* __restrict__ counter, float* __restrict__ out)
{
    __shared__ __align__(16) __hip_bfloat16 sA[2][128][32];   // 16 KB
    __shared__ __align__(16) __hip_bfloat16 sB[2][128][32];   // 16 KB -> 32 KB total
    // overlay region (valid only after the K-loop's final barrier):
    float* ovl   = (float*)&sA[0][0][0];     // 4096 floats
    float* sdiag = ovl;                      // [128]
    float* sred  = ovl + 128;                // [128][2][2] flattened
    float* fred  = ovl + 640;                // [4][10]
    float* fsmat = ovl + 680;                // [4][4]
    unsigned int* s_old = (unsigned int*)(ovl + 700);

    const int z = blockIdx.z;
    const __hip_bfloat16* Ah = z ? h1 : h0;
    const __hip_bfloat16* Al = z ? l1 : l0;
    const __hip_bfloat16* Bh = z ? h2 : h3;
    const __hip_bfloat16* Bl = z ? l2 : l3;
    const float* diag = z ? dt : dv;
    float* row_e = z ? row_et : row_ev;
    float* row_c = z ? row_ct : row_cv;

    const int tid = threadIdx.x;
    const int lane = tid & 63;
    const int w = tid >> 6;
    const int wy = w >> 1, wx = w & 1;
    const int bm = blockIdx.x * 128;
    const int bn = blockIdx.y * 128;

    f32x4 acc[4][4];
    for (int i = 0; i < 4; i++)
        for (int j = 0; j < 4; j++)
            acc[i][j] = (f32x4){0.f, 0.f, 0.f, 0.f};

    const int srow = lane >> 2;                               // 0..15
    const int lcol = (lane & 3) * 8;                          // LDS dst (natural)
    const int scolg = (((lane & 3) ^ ((lane >> 3) & 3))) * 8; // swizzled global k
    const int fr = lane & 15;
    const int pcs = ((lane >> 4) ^ ((fr >> 1) & 3)) * 8;      // swizzled read k

    for (int k0 = 0; k0 < C; k0 += 32) {
        for (int half = 0; half < 2; half++) {
            int rr = w * 16 + half * 64 + srow;
            size_t ga = (size_t)(bm + rr) * C + k0 + scolg;
            size_t gb = (size_t)(bn + rr) * C + k0 + scolg;
            gload16(Ah + ga, &sA[0][rr][lcol]);
            gload16(Al + ga, &sA[1][rr][lcol]);
            gload16(Bh + gb, &sB[0][rr][lcol]);
            gload16(Bl + gb, &sB[1][rr][lcol]);
        }
        __syncthreads();

        bf16x8 a_h[4], a_l[4], b_h[4], b_l[4];
        for (int i = 0; i < 4; i++) {
            a_h[i] = *(const bf16x8*)&sA[0][wy * 64 + i * 16 + fr][pcs];
            a_l[i] = *(const bf16x8*)&sA[1][wy * 64 + i * 16 + fr][pcs];
            b_h[i] = *(const bf16x8*)&sB[0][wx * 64 + i * 16 + fr][pcs];
            b_l[i] = *(const bf16x8*)&sB[1][wx * 64 + i * 16 + fr][pcs];
        }
        for (int i = 0; i < 4; i++)
            for (int j = 0; j < 4; j++) {
                acc[i][j] = __builtin_amdgcn_mfma_f32_16x16x32_bf16(a_h[i], b_h[j], acc[i][j], 0, 0, 0);
                acc[i][j] = __builtin_amdgcn_mfma_f32_16x16x32_bf16(a_h[i], b_l[j], acc[i][j], 0, 0, 0);
                acc[i][j] = __builtin_amdgcn_mfma_f32_16x16x32_bf16(a_l[i], b_h[j], acc[i][j], 0, 0, 0);
            }
        __syncthreads();
    }

    // ---- epilogue (overlay region now safe to use) ----
    if (tid < 128) sdiag[tid] = diag[bm + tid];
    __syncthreads();

    const int quad = lane >> 4;
    for (int i = 0; i < 4; i++) {
        for (int reg = 0; reg < 4; reg++) {
            int rloc = wy * 64 + i * 16 + quad * 4 + reg;
            int grow = bm + rloc;
            float d = sdiag[rloc];
            float e = 0.f, c = 0.f;
            for (int j = 0; j < 4; j++) {
                float s = acc[i][j][reg];
                int gcol = bn + wx * 64 + j * 16 + fr;
                e += __expf(10.f * s - 10.f);
                if (s > d && gcol != grow) c += 1.f;
            }
            for (int o = 1; o < 16; o <<= 1) {
                e += __shfl_xor(e, o);
                c += __shfl_xor(c, o);
            }
            if (fr == 0) { sred[(rloc * 2 + wx) * 2 + 0] = e; sred[(rloc * 2 + wx) * 2 + 1] = c; }
        }
    }
    __syncthreads();
    if (tid < 128) {
        atomicAdd(&row_e[bm + tid], sred[(tid * 2 + 0) * 2 + 0] + sred[(tid * 2 + 1) * 2 + 0]);
        atomicAdd(&row_c[bm + tid], sred[(tid * 2 + 0) * 2 + 1] + sred[(tid * 2 + 1) * 2 + 1]);
    }
    __syncthreads();

    // ---- completion counter; last of 2048 blocks finalizes ----
    if (tid == 0) {
        __threadfence();
        *s_old = atomicAdd(counter, 1u);
    }
    __syncthreads();
    if (*s_old != 2047) return;
    __threadfence();

    // ---- final combine (256 threads, ~96 KB of L2-hot reads) ----
    {
        const int lane2 = tid & 63;
        const int wv = tid >> 6;
        float vals[10];
        for (int k = 0; k < 10; k++) vals[k] = 0.f;
        for (int i = 0; i < 16; i++) {
            const int row = i * 256 + tid;
            float se = row_ev[row] + row_et[row];
            float pv = row_cv[row];
            float pt = row_ct[row];
            vals[0] += logf(se) + 10.f;
            vals[1] += (pv < 0.5f) ? 1.f : 0.f;
            vals[2] += (pv < 4.5f) ? 1.f : 0.f;
            vals[3] += (pv < 9.5f) ? 1.f : 0.f;
            vals[4] += pv;
            vals[5] += (pt < 0.5f) ? 1.f : 0.f;
            vals[6] += (pt < 4.5f) ? 1.f : 0.f;
            vals[7] += (pt < 9.5f) ? 1.f : 0.f;
            vals[8] += pt;
            vals[9] += __expf(10.f * dv[row] - 10.f) + __expf(10.f * dt[row] - 10.f);
        }
        for (int k = 0; k < 10; k++) {
            float v = vals[k];
            for (int o = 1; o < 64; o <<= 1) v += __shfl_xor(v, o);
            if (lane2 == 0) fred[wv * 10 + k] = v;
        }
        for (int m = 0; m < 4; m++) {
            float sd2 = 0.f;
            for (int h = 0; h < 2; h++) {
                int c = h * 256 + tid;
                float a = colsum[m * 512 + c];
                float q = colsq [m * 512 + c];
                float var = (q - a * a * (1.f / N)) * (1.f / (N - 1));
                sd2 += sqrtf(fmaxf(var, 0.f));
            }
            for (int o = 1; o < 64; o <<= 1) sd2 += __shfl_xor(sd2, o);
            if (lane2 == 0) fsmat[wv * 4 + m] = sd2;
        }
        __syncthreads();
        if (tid == 0) {
            float g[10];
            for (int k = 0; k < 10; k++)
                g[k] = fred[0 * 10 + k] + fred[1 * 10 + k] + fred[2 * 10 + k] + fred[3 * 10 + k];
            float stds[4];
            for (int m = 0; m < 4; m++)
                stds[m] = (fsmat[0 * 4 + m] + fsmat[1 * 4 + m] + fsmat[2 * 4 + m] + fsmat[3 * 4 + m]) * (1.f / 512.f);
            const float invN = 1.f / N;
            float nominator = logf(g[9]) + 10.f;
            out[0]  = g[0] * invN - nominator;
            out[1]  = stds[0];
            out[2]  = stds[1];
            out[3]  = stds[2];
            out[4]  = stds[3];
            out[5]  = g[1] * invN;
            out[6]  = g[2] * invN;
            out[7]  = g[3] * invN;
            out[8]  = g[4] * invN;
            out[9]  = g[5] * invN;
            out[10] = g[6] * invN;
            out[11] = g[7] * invN;
            out[12] = g[8] * invN;
        }
    }
}

extern "C" void kernel_launch(void* const* d_in, const int* in_sizes, int n_in,
                              void* d_out, int out_size, void* d_ws, size_t ws_size,
                              hipStream_t stream)
{
    char* p = (char*)d_ws;

    // --- zeroed accumulator region (contiguous) ---
    float* row_ev = (float*)p; p += N * 4;
    float* row_et = (float*)p; p += N * 4;
    float* row_cv = (float*)p; p += N * 4;
    float* row_ct = (float*)p; p += N * 4;
    float* colsum = (float*)p; p += 4 * 512 * 4;
    float* colsq  = (float*)p; p += 4 * 512 * 4;
    unsigned int* counter = (unsigned int*)p; p += 16;
    const size_t acc_bytes = (size_t)(p - (char*)d_ws);

    // --- plain workspace ---
    const size_t NE = (size_t)N * C;           // 2,097,152 elems
    const long mat_stride = 2 * NE;            // hi + lo, in bf16 elems
    __hip_bfloat16* hiA[4];
    __hip_bfloat16* loA[4];
    for (int m = 0; m < 4; m++) {
        hiA[m] = (__hip_bfloat16*)p; p += NE * 2;
        loA[m] = (__hip_bfloat16*)p; p += NE * 2;
    }
    float* dv = (float*)p; p += N * 4;
    float* dt = (float*)p; p += N * 4;

    hipMemsetAsync(d_ws, 0, acc_bytes, stream);

    // 1. paired single-pass prep: split x4 + diag + col-std atomics
    k_prep<<<dim3(512), 256, 0, stream>>>(
        (const float*)d_in[0], (const float*)d_in[1],
        (const float*)d_in[2], (const float*)d_in[3],
        hiA[0], mat_stride, dv, dt, colsum, colsq);

    // 2. both fused GEMMs (z selects) + atomic row epilogue + last-block fin
    k_gemm<<<dim3(32, 32, 2), 256, 0, stream>>>(
        hiA[0], loA[0], hiA[1], loA[1], hiA[2], loA[2], hiA[3], loA[3],
        dv, dt, row_ev, row_et, row_cv, row_ct,
        colsum, colsq, counter, (float*)d_out);
}

// Round 9
// 211.201 us; speedup vs baseline: 3.9980x; 3.9980x over previous
//
#include <hip/hip_runtime.h>
#include <hip/hip_bf16.h>

#define N 4096
#define C 512

typedef __attribute__((ext_vector_type(8))) short bf16x8;
typedef __attribute__((ext_vector_type(8))) short s16x8;
typedef __attribute__((ext_vector_type(4))) float f32x4;

__device__ inline float bf2f(__hip_bfloat16 h) { return __bfloat162float(h); }

__device__ inline void gload16(const void* g, void* l) {
    __builtin_amdgcn_global_load_lds(
        (__attribute__((address_space(1))) void*)(g),
        (__attribute__((address_space(3))) void*)(l),
        16, 0, 0);
}

// ================= kernel 1: single-pass paired prep ==========================
// 512 blocks x 256 threads. pair = b>>8 (0: v&pt -> dv, 1: t&pv -> dt),
// chunk = b&255 (16 rows). Wave w owns rows chunk*16 + w*4 .. +3.
__global__ __launch_bounds__(256) void k_prep(
    const float* __restrict__ s0, const float* __restrict__ s1f,
    const float* __restrict__ s2f, const float* __restrict__ s3,
    __hip_bfloat16* __restrict__ ws_hi0, long mat_stride,
    float* __restrict__ dv, float* __restrict__ dt,
    float* __restrict__ colsum, float* __restrict__ colsq)
{
    __shared__ float sa[4][512];
    __shared__ float sq[4][512];

    const int b = blockIdx.x;
    const int tid = threadIdx.x;
    const int lane = tid & 63;
    const int w = tid >> 6;

    const int pair = b >> 8;
    const int chunk = b & 255;
    const float* X = pair ? s1f : s0;        // t : v
    const float* B = pair ? s2f : s3;        // pv : pt
    const int mX = pair ? 1 : 0;
    const int mB = pair ? 2 : 3;
    __hip_bfloat16* hiX = ws_hi0 + (long)mX * mat_stride;
    __hip_bfloat16* loX = hiX + (long)N * C;
    __hip_bfloat16* hiB = ws_hi0 + (long)mB * mat_stride;
    __hip_bfloat16* loB = hiB + (long)N * C;
    float* dout = pair ? dt : dv;

    float aX[8], qX[8], aB[8], qB[8];
    for (int e = 0; e < 8; e++) { aX[e] = 0.f; qX[e] = 0.f; aB[e] = 0.f; qB[e] = 0.f; }

    const int row0 = chunk * 16 + w * 4;
    for (int i = 0; i < 4; i++) {
        const int row = row0 + i;
        const float4* x4 = (const float4*)(X + (size_t)row * C);
        const float4* b4 = (const float4*)(B + (size_t)row * C);
        float4 x0 = x4[lane * 2], x1 = x4[lane * 2 + 1];
        float4 b0 = b4[lane * 2], b1 = b4[lane * 2 + 1];

        float ss  = x0.x*x0.x + x0.y*x0.y + x0.z*x0.z + x0.w*x0.w
                  + x1.x*x1.x + x1.y*x1.y + x1.z*x1.z + x1.w*x1.w;
        float ssb = b0.x*b0.x + b0.y*b0.y + b0.z*b0.z + b0.w*b0.w
                  + b1.x*b1.x + b1.y*b1.y + b1.z*b1.z + b1.w*b1.w;
        float dot = x0.x*b0.x + x0.y*b0.y + x0.z*b0.z + x0.w*b0.w
                  + x1.x*b1.x + x1.y*b1.y + x1.z*b1.z + x1.w*b1.w;
        for (int o = 1; o < 64; o <<= 1) {       // 3 independent chains, interleaved
            ss  += __shfl_xor(ss, o);
            ssb += __shfl_xor(ssb, o);
            dot += __shfl_xor(dot, o);
        }
        float scX = 1.0f / fmaxf(sqrtf(ss), 1e-12f);
        float scB = 1.0f / fmaxf(sqrtf(ssb), 1e-12f);
        if (lane == 0) dout[row] = dot * scX * scB;

        float yx[8] = { x0.x*scX, x0.y*scX, x0.z*scX, x0.w*scX,
                        x1.x*scX, x1.y*scX, x1.z*scX, x1.w*scX };
        float yb[8] = { b0.x*scB, b0.y*scB, b0.z*scB, b0.w*scB,
                        b1.x*scB, b1.y*scB, b1.z*scB, b1.w*scB };
        __hip_bfloat16 hvx[8], lvx[8], hvb[8], lvb[8];
        for (int e = 0; e < 8; e++) {
            hvx[e] = __float2bfloat16(yx[e]);
            lvx[e] = __float2bfloat16(yx[e] - bf2f(hvx[e]));
            aX[e] += yx[e]; qX[e] += yx[e] * yx[e];
            hvb[e] = __float2bfloat16(yb[e]);
            lvb[e] = __float2bfloat16(yb[e] - bf2f(hvb[e]));
            aB[e] += yb[e]; qB[e] += yb[e] * yb[e];
        }
        size_t base = (size_t)row * C + lane * 8;
        *(s16x8*)(hiX + base) = *(s16x8*)hvx;
        *(s16x8*)(loX + base) = *(s16x8*)lvx;
        *(s16x8*)(hiB + base) = *(s16x8*)hvb;
        *(s16x8*)(loB + base) = *(s16x8*)lvb;
    }

    for (int e = 0; e < 8; e++) { sa[w][lane*8+e] = aX[e]; sq[w][lane*8+e] = qX[e]; }
    __syncthreads();
    for (int c = tid; c < 512; c += 256) {
        atomicAdd(&colsum[mX * 512 + c], sa[0][c] + sa[1][c] + sa[2][c] + sa[3][c]);
        atomicAdd(&colsq [mX * 512 + c], sq[0][c] + sq[1][c] + sq[2][c] + sq[3][c]);
    }
    __syncthreads();
    for (int e = 0; e < 8; e++) { sa[w][lane*8+e] = aB[e]; sq[w][lane*8+e] = qB[e]; }
    __syncthreads();
    for (int c = tid; c < 512; c += 256) {
        atomicAdd(&colsum[mB * 512 + c], sa[0][c] + sa[1][c] + sa[2][c] + sa[3][c]);
        atomicAdd(&colsq [mB * 512 + c], sq[0][c] + sq[1][c] + sq[2][c] + sq[3][c]);
    }
}

// ================= kernel 2: fused split-GEMM + atomic epilogue ===============
// ROUND-7 VERIFIED CONFIG — do not re-add a min-waves launch bound:
// this kernel needs ~160 regs/wave (64 AGPR acc + staging); with the ~512
// VGPR/SIMD pool (m69) any bound >3 waves/SIMD forces spill-to-scratch
// (round 8: VGPR 96->48, 3.3 GB spill traffic, 776 us).
// C-tile 128x128, BK=32, 4 waves (2x2), 3 MFMA per frag pair.
// XOR k-block swizzle (round-5 verified: SQ_LDS_BANK_CONFLICT == 0).
__global__ __launch_bounds__(256) void k_gemm(
    const __hip_bfloat16* __restrict__ h0, const __hip_bfloat16* __restrict__ l0,
    const __hip_bfloat16* __restrict__ h1, const __hip_bfloat16* __restrict__ l1,
    const __hip_bfloat16* __restrict__ h2, const __hip_bfloat16* __restrict__ l2,
    const __hip_bfloat16* __restrict__ h3, const __hip_bfloat16* __restrict__ l3,
    const float* __restrict__ dv, const float* __restrict__ dt,
    float* __restrict__ row_ev, float* __restrict__ row_et,
    float* __restrict__ row_cv, float* __restrict__ row_ct)
{
    __shared__ __align__(16) __hip_bfloat16 sA[2][128][32];
    __shared__ __align__(16) __hip_bfloat16 sB[2][128][32];
    __shared__ float sdiag[128];
    __shared__ float sred[128][2][2];

    const int z = blockIdx.z;
    const __hip_bfloat16* Ah = z ? h1 : h0;
    const __hip_bfloat16* Al = z ? l1 : l0;
    const __hip_bfloat16* Bh = z ? h2 : h3;
    const __hip_bfloat16* Bl = z ? l2 : l3;
    const float* diag = z ? dt : dv;
    float* row_e = z ? row_et : row_ev;
    float* row_c = z ? row_ct : row_cv;

    const int tid = threadIdx.x;
    const int lane = tid & 63;
    const int w = tid >> 6;
    const int wy = w >> 1, wx = w & 1;
    const int bm = blockIdx.x * 128;
    const int bn = blockIdx.y * 128;

    if (tid < 128) sdiag[tid] = diag[bm + tid];

    f32x4 acc[4][4];
    for (int i = 0; i < 4; i++)
        for (int j = 0; j < 4; j++)
            acc[i][j] = (f32x4){0.f, 0.f, 0.f, 0.f};

    const int srow = lane >> 2;                               // 0..15
    const int lcol = (lane & 3) * 8;                          // LDS dst (natural)
    const int scolg = (((lane & 3) ^ ((lane >> 3) & 3))) * 8; // swizzled global k
    const int fr = lane & 15;
    const int pcs = ((lane >> 4) ^ ((fr >> 1) & 3)) * 8;      // swizzled read k

    for (int k0 = 0; k0 < C; k0 += 32) {
        for (int half = 0; half < 2; half++) {
            int rr = w * 16 + half * 64 + srow;
            size_t ga = (size_t)(bm + rr) * C + k0 + scolg;
            size_t gb = (size_t)(bn + rr) * C + k0 + scolg;
            gload16(Ah + ga, &sA[0][rr][lcol]);
            gload16(Al + ga, &sA[1][rr][lcol]);
            gload16(Bh + gb, &sB[0][rr][lcol]);
            gload16(Bl + gb, &sB[1][rr][lcol]);
        }
        __syncthreads();

        bf16x8 a_h[4], a_l[4], b_h[4], b_l[4];
        for (int i = 0; i < 4; i++) {
            a_h[i] = *(const bf16x8*)&sA[0][wy * 64 + i * 16 + fr][pcs];
            a_l[i] = *(const bf16x8*)&sA[1][wy * 64 + i * 16 + fr][pcs];
            b_h[i] = *(const bf16x8*)&sB[0][wx * 64 + i * 16 + fr][pcs];
            b_l[i] = *(const bf16x8*)&sB[1][wx * 64 + i * 16 + fr][pcs];
        }
        for (int i = 0; i < 4; i++)
            for (int j = 0; j < 4; j++) {
                acc[i][j] = __builtin_amdgcn_mfma_f32_16x16x32_bf16(a_h[i], b_h[j], acc[i][j], 0, 0, 0);
                acc[i][j] = __builtin_amdgcn_mfma_f32_16x16x32_bf16(a_h[i], b_l[j], acc[i][j], 0, 0, 0);
                acc[i][j] = __builtin_amdgcn_mfma_f32_16x16x32_bf16(a_l[i], b_h[j], acc[i][j], 0, 0, 0);
            }
        __syncthreads();
    }

    // epilogue: C/D layout row=(lane>>4)*4+reg, col=lane&15
    const int quad = lane >> 4;
    for (int i = 0; i < 4; i++) {
        for (int reg = 0; reg < 4; reg++) {
            int rloc = wy * 64 + i * 16 + quad * 4 + reg;
            int grow = bm + rloc;
            float d = sdiag[rloc];
            float e = 0.f, c = 0.f;
            for (int j = 0; j < 4; j++) {
                float s = acc[i][j][reg];
                int gcol = bn + wx * 64 + j * 16 + fr;
                e += __expf(10.f * s - 10.f);
                if (s > d && gcol != grow) c += 1.f;
            }
            for (int o = 1; o < 16; o <<= 1) {
                e += __shfl_xor(e, o);
                c += __shfl_xor(c, o);
            }
            if (fr == 0) { sred[rloc][wx][0] = e; sred[rloc][wx][1] = c; }
        }
    }
    __syncthreads();
    if (tid < 128) {
        atomicAdd(&row_e[bm + tid], sred[tid][0][0] + sred[tid][1][0]);
        atomicAdd(&row_c[bm + tid], sred[tid][0][1] + sred[tid][1][1]);
    }
}

// ================= kernel 3: tiny finalization (1 block, 96 KB of L2-hot reads)
__global__ __launch_bounds__(256) void k_fin(
    const float* __restrict__ dv, const float* __restrict__ dt,
    const float* __restrict__ row_ev, const float* __restrict__ row_et,
    const float* __restrict__ row_cv, const float* __restrict__ row_ct,
    const float* __restrict__ colsum, const float* __restrict__ colsq,
    float* __restrict__ out)
{
    const int t = threadIdx.x;
    const int lane = t & 63;
    const int wv = t >> 6;

    float vals[10];
    for (int k = 0; k < 10; k++) vals[k] = 0.f;
    for (int i = 0; i < 16; i++) {
        const int row = i * 256 + t;
        float se = row_ev[row] + row_et[row];
        float pv = row_cv[row];
        float pt = row_ct[row];
        vals[0] += logf(se) + 10.f;
        vals[1] += (pv < 0.5f) ? 1.f : 0.f;
        vals[2] += (pv < 4.5f) ? 1.f : 0.f;
        vals[3] += (pv < 9.5f) ? 1.f : 0.f;
        vals[4] += pv;
        vals[5] += (pt < 0.5f) ? 1.f : 0.f;
        vals[6] += (pt < 4.5f) ? 1.f : 0.f;
        vals[7] += (pt < 9.5f) ? 1.f : 0.f;
        vals[8] += pt;
        vals[9] += __expf(10.f * dv[row] - 10.f) + __expf(10.f * dt[row] - 10.f);
    }
    __shared__ float red[4][10];
    for (int k = 0; k < 10; k++) {
        float v = vals[k];
        for (int o = 1; o < 64; o <<= 1) v += __shfl_xor(v, o);
        if (lane == 0) red[wv][k] = v;
    }

    // stds: each thread handles cols t and t+256 of each matrix
    __shared__ float smat[4][4];
    for (int m = 0; m < 4; m++) {
        float sd2 = 0.f;
        for (int h = 0; h < 2; h++) {
            int c = h * 256 + t;
            float a = colsum[m * 512 + c];
            float q = colsq [m * 512 + c];
            float var = (q - a * a * (1.f / N)) * (1.f / (N - 1));
            sd2 += sqrtf(fmaxf(var, 0.f));
        }
        for (int o = 1; o < 64; o <<= 1) sd2 += __shfl_xor(sd2, o);
        if (lane == 0) smat[wv][m] = sd2;
    }
    __syncthreads();
    if (t == 0) {
        float g[10];
        for (int k = 0; k < 10; k++)
            g[k] = red[0][k] + red[1][k] + red[2][k] + red[3][k];
        float stds[4];
        for (int m = 0; m < 4; m++)
            stds[m] = (smat[0][m] + smat[1][m] + smat[2][m] + smat[3][m]) * (1.f / 512.f);
        const float invN = 1.f / N;
        float nominator = logf(g[9]) + 10.f;
        out[0]  = g[0] * invN - nominator;
        out[1]  = stds[0];
        out[2]  = stds[1];
        out[3]  = stds[2];
        out[4]  = stds[3];
        out[5]  = g[1] * invN;
        out[6]  = g[2] * invN;
        out[7]  = g[3] * invN;
        out[8]  = g[4] * invN;
        out[9]  = g[5] * invN;
        out[10] = g[6] * invN;
        out[11] = g[7] * invN;
        out[12] = g[8] * invN;
    }
}

extern "C" void kernel_launch(void* const* d_in, const int* in_sizes, int n_in,
                              void* d_out, int out_size, void* d_ws, size_t ws_size,
                              hipStream_t stream)
{
    char* p = (char*)d_ws;

    // --- zeroed accumulator region (contiguous, 80 KB) ---
    float* row_ev = (float*)p; p += N * 4;
    float* row_et = (float*)p; p += N * 4;
    float* row_cv = (float*)p; p += N * 4;
    float* row_ct = (float*)p; p += N * 4;
    float* colsum = (float*)p; p += 4 * 512 * 4;
    float* colsq  = (float*)p; p += 4 * 512 * 4;
    const size_t acc_bytes = (size_t)(p - (char*)d_ws);

    // --- plain workspace ---
    const size_t NE = (size_t)N * C;           // 2,097,152 elems
    const long mat_stride = 2 * NE;            // hi + lo, in bf16 elems
    __hip_bfloat16* hiA[4];
    __hip_bfloat16* loA[4];
    for (int m = 0; m < 4; m++) {
        hiA[m] = (__hip_bfloat16*)p; p += NE * 2;
        loA[m] = (__hip_bfloat16*)p; p += NE * 2;
    }
    float* dv = (float*)p; p += N * 4;
    float* dt = (float*)p; p += N * 4;

    hipMemsetAsync(d_ws, 0, acc_bytes, stream);

    // 1. paired single-pass prep: split x4 + diag + col-std atomics
    k_prep<<<dim3(512), 256, 0, stream>>>(
        (const float*)d_in[0], (const float*)d_in[1],
        (const float*)d_in[2], (const float*)d_in[3],
        hiA[0], mat_stride, dv, dt, colsum, colsq);

    // 2. both fused GEMMs in one dispatch (z selects), atomic row epilogue
    k_gemm<<<dim3(32, 32, 2), 256, 0, stream>>>(
        hiA[0], loA[0], hiA[1], loA[1], hiA[2], loA[2], hiA[3], loA[3],
        dv, dt, row_ev, row_et, row_cv, row_ct);

    // 3. tiny finalization (single block; inputs are L2-hot)
    k_fin<<<dim3(1), 256, 0, stream>>>(
        dv, dt, row_ev, row_et, row_cv, row_ct, colsum, colsq, (float*)d_out);
}